// Round 1
// baseline (142.057 us; speedup 1.0000x reference)
//
#include <hip/hip_runtime.h>
#include <hip/hip_fp16.h>
#include <type_traits>

typedef _Float16 f16;
typedef _Float16 f16x8 __attribute__((ext_vector_type(8)));
typedef float f32x4 __attribute__((ext_vector_type(4)));

#define NSZ 256
#define NIMG 384

// Swizzled LDS index (in halves) for tile [128 rows][64 k-halves].
// XOR of k-group (8-half = 16B granules) with row&7 -> conflict-free ds_read_b128.
__device__ __forceinline__ int swz(int r, int kh) {
  return r * 64 + (kh ^ ((r & 7) << 3));
}

// Build C (f16, [k][h]), C^T (f16, [h][k]) and per-batch g[b][n] = exp(-f_n^2 * tau_b).
__global__ void prep_kernel(f16* __restrict__ Cm, f16* __restrict__ CTm,
                            float* __restrict__ g, const float* __restrict__ t) {
  int k = blockIdx.x;
  int h = threadIdx.x;
  double scale = (k == 0) ? 0.0625 : 0.08838834764831844; // sqrt(1/256), sqrt(2/256)
  double val = cos(3.14159265358979323846 * ((double)h + 0.5) * (double)k / 256.0) * scale;
  f16 vh = (f16)((float)val);
  Cm[k * NSZ + h] = vh;
  CTm[h * NSZ + k] = vh;
  if (k < 128) {
    float tb = t[k];
    float sg = expf(-0.69314718055994531f * (1.0f - tb) + 2.99573227355399099f * tb);
    float tau = 0.5f * sg * sg;
    float f = 3.14159265358979f * (float)h / 256.0f;
    g[k * NSZ + h] = expf(-f * f * tau);
  }
}

// NT GEMM: OUT[i][j] = sum_k A[i][k] * B[j][k], per image (A shared).
// A: f16 [256][256] row-major. B: per-image [256][256] row-major (TB = float or f16).
// 128x128 tile per block, BK=64, 4 waves (2x2), 16x16x32 f16 MFMA, 4x4 frags/wave.
template <typename TB, typename TO, bool EPI>
__global__ __launch_bounds__(256, 2) void gemm_nt(
    const f16* __restrict__ A, const TB* __restrict__ Bg,
    TO* __restrict__ Og, const float* __restrict__ gt) {
  __shared__ f16 As[128 * 64];
  __shared__ f16 Bs[128 * 64];

  int bid = blockIdx.x;
  int img = bid >> 2;
  int tm = (bid >> 1) & 1;
  int tn = bid & 1;

  const f16* Ab = A + tm * 128 * NSZ;
  const TB* Bb = Bg + (size_t)img * NSZ * NSZ + (size_t)tn * 128 * NSZ;

  int t = threadIdx.x;
  int lane = t & 63;
  int wave = t >> 6;
  int wr = wave >> 1;
  int wc = wave & 1;

  f32x4 acc[4][4];
#pragma unroll
  for (int i = 0; i < 4; i++)
#pragma unroll
    for (int j = 0; j < 4; j++) {
      f32x4 z = {0.f, 0.f, 0.f, 0.f};
      acc[i][j] = z;
    }

  for (int kk = 0; kk < NSZ; kk += 64) {
    __syncthreads();
    // Stage A-tile and B-tile: 1024 8-half chunks each, 256 threads x 4 chunks.
#pragma unroll
    for (int c = 0; c < 4; c++) {
      int cid = t + c * 256;
      int r = cid >> 3;
      int gch = cid & 7;
      // A (always f16)
      f16x8 av = *(const f16x8*)(Ab + r * NSZ + kk + gch * 8);
      *(f16x8*)(&As[swz(r, gch * 8)]) = av;
      // B
      if constexpr (std::is_same<TB, float>::value) {
        const float* bs = Bb + r * NSZ + kk + gch * 8;
        float4 x0 = *(const float4*)(bs);
        float4 x1 = *(const float4*)(bs + 4);
        f16x8 bv;
        bv[0] = (f16)x0.x; bv[1] = (f16)x0.y; bv[2] = (f16)x0.z; bv[3] = (f16)x0.w;
        bv[4] = (f16)x1.x; bv[5] = (f16)x1.y; bv[6] = (f16)x1.z; bv[7] = (f16)x1.w;
        *(f16x8*)(&Bs[swz(r, gch * 8)]) = bv;
      } else {
        f16x8 bv = *(const f16x8*)(Bb + r * NSZ + kk + gch * 8);
        *(f16x8*)(&Bs[swz(r, gch * 8)]) = bv;
      }
    }
    __syncthreads();

#pragma unroll
    for (int ks = 0; ks < 64; ks += 32) {
      int kcol = ks + (lane >> 4) * 8;
      f16x8 af[4], bf[4];
      int rA = wr * 64 + (lane & 15);
#pragma unroll
      for (int i = 0; i < 4; i++)
        af[i] = *(const f16x8*)(&As[swz(rA + i * 16, kcol)]);
      int rB = wc * 64 + (lane & 15);
#pragma unroll
      for (int j = 0; j < 4; j++)
        bf[j] = *(const f16x8*)(&Bs[swz(rB + j * 16, kcol)]);
#pragma unroll
      for (int i = 0; i < 4; i++)
#pragma unroll
        for (int j = 0; j < 4; j++)
          acc[i][j] = __builtin_amdgcn_mfma_f32_16x16x32_f16(af[i], bf[j], acc[i][j], 0, 0, 0);
    }
  }

  // Epilogue: C/D layout col=lane&15, row=(lane>>4)*4+v.
  TO* Ob = Og + (size_t)img * NSZ * NSZ;
  int b = img / 3;
  int row0 = tm * 128 + wr * 64;
  int col0 = tn * 128 + wc * 64 + (lane & 15);
#pragma unroll
  for (int i = 0; i < 4; i++) {
#pragma unroll
    for (int j = 0; j < 4; j++) {
      int c = col0 + j * 16;
      float gn = 0.f;
      if constexpr (EPI) gn = gt[b * NSZ + c];
#pragma unroll
      for (int v = 0; v < 4; v++) {
        int r = row0 + i * 16 + (lane >> 4) * 4 + v;
        float val = acc[i][j][v];
        if constexpr (EPI) {
          float gk = gt[b * NSZ + r];
          float fade = gk * gn;
          float s = (fade < 0.01f) ? 0.001f : fade * 0.999f + 0.001f;
          val *= s;
        }
        Ob[r * NSZ + c] = (TO)val;
      }
    }
  }
}

extern "C" void kernel_launch(void* const* d_in, const int* in_sizes, int n_in,
                              void* d_out, int out_size, void* d_ws, size_t ws_size,
                              hipStream_t stream) {
  const float* x = (const float*)d_in[0];
  const float* t = (const float*)d_in[1];
  float* out = (float*)d_out;

  char* ws = (char*)d_ws;
  float* g = (float*)ws;                       // 128*256*4   = 131072 B
  f16* Cm = (f16*)(ws + 131072);               // 256*256*2   = 131072 B
  f16* CTm = (f16*)(ws + 262144);              // 256*256*2   = 131072 B
  f16* V = (f16*)(ws + 393216);                // 384*256*256*2 = 50331648 B
  f16* E = (f16*)d_out;                        // scratch inside d_out (consumed before stage 4 writes)

  prep_kernel<<<256, 256, 0, stream>>>(Cm, CTm, g, t);

  const int grid = NIMG * 4;
  // Stage 1: V1[n][h] = sum_w C[n][w] X[h][w]
  gemm_nt<float, f16, false><<<grid, 256, 0, stream>>>(Cm, x, V, nullptr);
  // Stage 2: E[k][n] = S ⊙ sum_h C[k][h] V1[n][h]
  gemm_nt<f16, f16, true><<<grid, 256, 0, stream>>>(Cm, V, E, g);
  // Stage 3: V3[w][k] = sum_n CT[w][n] E[k][n]
  gemm_nt<f16, f16, false><<<grid, 256, 0, stream>>>(CTm, E, V, nullptr);
  // Stage 4: Y[h][w] = sum_k CT[h][k] V3[w][k]
  gemm_nt<f16, float, false><<<grid, 256, 0, stream>>>(CTm, V, out, nullptr);
}

// Round 2
// 121.062 us; speedup vs baseline: 1.1734x; 1.1734x over previous
//
#include <hip/hip_runtime.h>
#include <hip/hip_fp16.h>

typedef _Float16 f16;
typedef _Float16 f16x8 __attribute__((ext_vector_type(8)));
typedef _Float16 f16x4 __attribute__((ext_vector_type(4)));
typedef float f32x4 __attribute__((ext_vector_type(4)));

#define NSZ 256
#define NIMG 384

// Swizzled LDS index (in halves): row r, half-col c. XOR 8-half (16B) granule by row&7.
__device__ __forceinline__ int sw(int r, int c) {
  return r * NSZ + (c ^ ((r & 7) << 3));
}

// Build C (f16, [k][h]), C^T (f16, [h][k]) and per-batch g[b][n] = exp(-f_n^2 * tau_b).
__global__ void prep_kernel(f16* __restrict__ Cm, f16* __restrict__ CTm,
                            float* __restrict__ g, const float* __restrict__ t) {
  int k = blockIdx.x;
  int h = threadIdx.x;
  double scale = (k == 0) ? 0.0625 : 0.08838834764831844; // sqrt(1/256), sqrt(2/256)
  double val = cos(3.14159265358979323846 * ((double)h + 0.5) * (double)k / 256.0) * scale;
  f16 vh = (f16)((float)val);
  Cm[k * NSZ + h] = vh;
  CTm[h * NSZ + k] = vh;
  if (k < 128) {
    float tb = t[k];
    float sg = expf(-0.69314718055994531f * (1.0f - tb) + 2.99573227355399099f * tb);
    float tau = 0.5f * sg * sg;
    float f = 3.14159265358979f * (float)h / 256.0f;
    g[k * NSZ + h] = expf(-f * f * tau);
  }
}

// One NT GEMM stage: R[r][c] = sum_k Op1[r][k] * Op2[c][k], r in wave's 128-row band,
// c in wave's 64-col band. OP1_LDS selects whether Op1 comes from LDS (swizzled) or
// the global table T; the other operand takes the other source.
template <bool OP1_LDS>
__device__ __forceinline__ void do_gemm(const f16* L, const f16* __restrict__ T,
                                        int r0, int c0, int lrow, int lk,
                                        f32x4 (&acc)[8][4]) {
#pragma unroll
  for (int fi = 0; fi < 8; ++fi)
#pragma unroll
    for (int fj = 0; fj < 4; ++fj) {
      f32x4 z = {0.f, 0.f, 0.f, 0.f};
      acc[fi][fj] = z;
    }
  for (int ks = 0; ks < 8; ++ks) {
    int kh = ks * 32 + lk;
    f16x8 o1[8], o2[4];
#pragma unroll
    for (int fi = 0; fi < 8; ++fi) {
      int row = r0 + fi * 16 + lrow;
      if constexpr (OP1_LDS)
        o1[fi] = *(const f16x8*)&L[sw(row, kh)];
      else
        o1[fi] = *(const f16x8*)&T[row * NSZ + kh];
    }
#pragma unroll
    for (int fj = 0; fj < 4; ++fj) {
      int row = c0 + fj * 16 + lrow;
      if constexpr (OP1_LDS)
        o2[fj] = *(const f16x8*)&T[row * NSZ + kh];
      else
        o2[fj] = *(const f16x8*)&L[sw(row, kh)];
    }
#pragma unroll
    for (int fi = 0; fi < 8; ++fi)
#pragma unroll
      for (int fj = 0; fj < 4; ++fj)
        acc[fi][fj] = __builtin_amdgcn_mfma_f32_16x16x32_f16(o1[fi], o2[fj], acc[fi][fj], 0, 0, 0);
  }
}

// Transposed writeback: LDS[c][r] = R[r][c]; each lane packs its 4 consecutive
// r-values (v=0..3) into one 8B ds_write.
__device__ __forceinline__ void writeT(f16* L, int r0, int c0, int lrow, int lv4,
                                       const f32x4 (&acc)[8][4]) {
#pragma unroll
  for (int fi = 0; fi < 8; ++fi) {
    int rp = r0 + fi * 16 + lv4;
#pragma unroll
    for (int fj = 0; fj < 4; ++fj) {
      int c = c0 + fj * 16 + lrow;
      f16x4 h;
      h[0] = (f16)acc[fi][fj][0];
      h[1] = (f16)acc[fi][fj][1];
      h[2] = (f16)acc[fi][fj][2];
      h[3] = (f16)acc[fi][fj][3];
      *(f16x4*)&L[sw(c, rp)] = h;
    }
  }
}

__global__ __launch_bounds__(512, 1) void fused_kernel(
    const float* __restrict__ x, float* __restrict__ out,
    const f16* __restrict__ Cm, const f16* __restrict__ CTm,
    const float* __restrict__ g) {
  __shared__ f16 L[NSZ * NSZ];  // 128 KiB

  const int img = blockIdx.x;
  const int b = img / 3;
  const float* X = x + (size_t)img * NSZ * NSZ;
  float* Y = out + (size_t)img * NSZ * NSZ;

  const int t = threadIdx.x;
  const int lane = t & 63;
  const int wave = t >> 6;
  const int wr = wave >> 2;  // 0..1
  const int wc = wave & 3;   // 0..3
  const int r0 = wr * 128;
  const int c0 = wc * 64;
  const int lrow = lane & 15;
  const int lk = (lane >> 4) * 8;
  const int lv4 = (lane >> 4) * 4;

  // ---- Load X (fp32) -> LDS f16, swizzled. 8192 granules of 8 halves.
  for (int it = 0; it < 16; ++it) {
    int gid = it * 512 + t;
    int r = gid >> 5;
    int c8 = (gid & 31) << 3;
    const float* s = X + r * NSZ + c8;
    float4 a0 = *(const float4*)s;
    float4 a1 = *(const float4*)(s + 4);
    f16x8 v;
    v[0] = (f16)a0.x; v[1] = (f16)a0.y; v[2] = (f16)a0.z; v[3] = (f16)a0.w;
    v[4] = (f16)a1.x; v[5] = (f16)a1.y; v[6] = (f16)a1.z; v[7] = (f16)a1.w;
    *(f16x8*)&L[sw(r, c8)] = v;
  }
  __syncthreads();

  f32x4 acc[8][4];

  // S1: R[h][n] = sum_w L0[h,w] * Cm[n,w]   (L0 = X)
  do_gemm<true>(L, Cm, r0, c0, lrow, lk, acc);
  __syncthreads();
  writeT(L, r0, c0, lrow, lv4, acc);   // L1[n][h]
  __syncthreads();

  // S2: R[k][n] = sum_h Cm[k,h] * L1[n,h]  (= dct_x), then exact scale.
  do_gemm<false>(L, Cm, r0, c0, lrow, lk, acc);
  {
    const float* gb = g + b * NSZ;
#pragma unroll
    for (int fi = 0; fi < 8; ++fi) {
      float4 gk = *(const float4*)&gb[r0 + fi * 16 + lv4];
      float gkv[4] = {gk.x, gk.y, gk.z, gk.w};
#pragma unroll
      for (int fj = 0; fj < 4; ++fj) {
        float gn = gb[c0 + fj * 16 + lrow];
#pragma unroll
        for (int v = 0; v < 4; ++v) {
          float fade = gkv[v] * gn;
          float s = (fade < 0.01f) ? 0.001f : (fade * 0.999f + 0.001f);
          acc[fi][fj][v] *= s;
        }
      }
    }
  }
  __syncthreads();
  writeT(L, r0, c0, lrow, lv4, acc);   // L2[n][k]
  __syncthreads();

  // S3: R[n][h] = sum_k L2[n,k] * CTm[h,k]
  do_gemm<true>(L, CTm, r0, c0, lrow, lk, acc);
  __syncthreads();
  writeT(L, r0, c0, lrow, lv4, acc);   // L3[h][n]
  __syncthreads();

  // S4: R[h][w] = sum_n L3[h,n] * CTm[w,n]  -> global Y
  do_gemm<true>(L, CTm, r0, c0, lrow, lk, acc);
#pragma unroll
  for (int fi = 0; fi < 8; ++fi) {
    int r = r0 + fi * 16 + lv4;
#pragma unroll
    for (int fj = 0; fj < 4; ++fj) {
      int c = c0 + fj * 16 + lrow;
#pragma unroll
      for (int v = 0; v < 4; ++v)
        Y[(size_t)(r + v) * NSZ + c] = acc[fi][fj][v];
    }
  }
}

extern "C" void kernel_launch(void* const* d_in, const int* in_sizes, int n_in,
                              void* d_out, int out_size, void* d_ws, size_t ws_size,
                              hipStream_t stream) {
  const float* x = (const float*)d_in[0];
  const float* t = (const float*)d_in[1];
  float* out = (float*)d_out;

  char* ws = (char*)d_ws;
  float* g = (float*)ws;           // 128*256*4 = 131072 B
  f16* Cm = (f16*)(ws + 131072);   // 256*256*2 = 131072 B
  f16* CTm = (f16*)(ws + 262144);  // 256*256*2 = 131072 B

  prep_kernel<<<256, 256, 0, stream>>>(Cm, CTm, g, t);
  fused_kernel<<<NIMG, 512, 0, stream>>>(x, out, Cm, CTm, g);
}